// Round 7
// baseline (2026.428 us; speedup 1.0000x reference)
//
#include <hip/hip_runtime.h>
#include <math.h>

#define Bx 16
#define Cx 64
#define Hx 128
#define Wx 128
#define HWx (Hx * Wx)

#define TW 32
#define TH 8
#define CCH 8
#define HALO_W (TW + 2)
#define HALO_H (TH + 2)
#define CPLANE (HALO_H * HALO_W)          // 340
#define CHUNK_ELEMS (CCH * CPLANE)        // 2720
#define NPF ((CHUNK_ELEMS + 255) / 256)   // 11
#define NCHUNK (Cx / CCH)                 // 8

// workspace layout (float offsets)
#define WS_CWT   0                         // cwT[c*64+o]            4096
#define WS_GPACK 4096                      // gpack12[c*96+rg*12+k]  6144  (rg=r*2+g)
#define WS_KERN  10240                     // per-b [c*36+k*4+g]     16*2304
#define WS_ATT   47104                     // per-b [c*4+r]          16*256

// ---------------- prep: hypernetwork + weight repacking (unchanged, passing) ----------------
__global__ __launch_bounds__(256)
void da_prep(const float* __restrict__ x_deg,
             const float* __restrict__ kw1,
             const float* __restrict__ kw2,
             const float* __restrict__ convw,
             const float* __restrict__ ca_w1,
             const float* __restrict__ ca_w2,
             const float* __restrict__ g1w,
             const float* __restrict__ g2w,
             float* __restrict__ ws)
{
    const int b = blockIdx.x;
    const int tid = threadIdx.x;

    if (b == Bx) {
        for (int i = tid; i < 4096; i += 256) {           // cwT[c*64+o] = convw[o*64+c]
            const int o = i >> 6, c = i & 63;
            ws[WS_CWT + c * 64 + o] = convw[o * 64 + c];
        }
        for (int i = tid; i < 6144; i += 256) {           // gpack12[c][rg=r*2+g][12]
            const int c = i / 96;
            int rem = i - c * 96;
            const int rg = rem / 12;
            const int k  = rem - rg * 12;
            const int r = rg >> 1;
            const int g = rg & 1;
            const float* src = g ? g2w : g1w;
            ws[WS_GPACK + i] = (k < 9) ? src[(r * Cx + c) * 9 + k] : 0.f;
        }
        return;
    }

    __shared__ float h1[16];
    __shared__ float a1[16];
    if (tid < 32) {
        const int j = tid & 15;
        const float* wsrc = (tid < 16) ? (kw1 + j * Cx) : (ca_w1 + j * Cx);
        float acc = 0.f;
        #pragma unroll 8
        for (int c = 0; c < Cx; ++c) acc = fmaf(x_deg[b * Cx + c], wsrc[c], acc);
        acc = acc > 0.f ? acc : 0.1f * acc;               // leaky_relu 0.1
        if (tid < 16) h1[j] = acc; else a1[j] = acc;
    }
    __syncthreads();

    for (int o4 = tid; o4 < 4 * 576; o4 += 256) {
        const int g = o4 / 576;
        const int o = o4 - g * 576;
        float acc = 0.f;
        #pragma unroll
        for (int i = 0; i < 4; ++i)
            acc = fmaf(h1[g * 4 + i], kw2[(g * 576 + o) * 4 + i], acc);
        const int c = o / 9;
        const int k = o - c * 9;
        ws[WS_KERN + b * 2304 + c * 36 + k * 4 + g] = acc;
    }
    {
        const int r = tid >> 6;
        const int c = tid & 63;
        float acc = 0.f;
        #pragma unroll
        for (int i = 0; i < 4; ++i)
            acc = fmaf(a1[r * 4 + i], ca_w2[(r * Cx + c) * 4 + i], acc);
        ws[WS_ATT + b * 256 + c * 4 + r] = 1.f / (1.f + expf(-acc));
    }
}

// ---------------- main fused kernel: round-6 skeleton + double-buffered staging ----------------
// Spill discipline (rounds 2-5 lesson): NO persistent register arrays besides
// ga[8]/y[64]; staging transients (addr + loaded value) are recomputed inline
// and die at each phase barrier. All register arrays statically indexed.
__global__ __launch_bounds__(256, 2)
void da_main(const float* __restrict__ x0,
             const float* __restrict__ ws,
             const float* __restrict__ g1b,
             const float* __restrict__ g2b,
             const float* __restrict__ convb,
             float* __restrict__ out)
{
    const int b  = blockIdx.z;
    const int h0 = blockIdx.y * TH;
    const int w0 = blockIdx.x * TW;
    const int tid = threadIdx.x;
    const int tx = tid & (TW - 1);
    const int ty = tid >> 5;

    __shared__ float sx[2][CHUNK_ELEMS];              // ping-pong x chunk (halo)
    __shared__ __align__(16) float sgp[6144];         // guide weights [c][rg][12]
    __shared__ __align__(16) float scw[4096];         // cwT [c][o]
    __shared__ float skern[2304];                     // [c][k][r]
    __shared__ float satt[256];                       // [c][r]
    // LDS total ~71 KB -> 2 blocks/CU

    const float* xb  = x0 + (size_t)b * Cx * HWx;
    const float* kws = ws + WS_KERN + b * 2304;
    const float* aws = ws + WS_ATT  + b * 256;

    // inline staging: load -> ds_write, fully unrolled so loads batch in flight
    auto STAGE = [&](int nch, int dbuf) {
        const float* src = xb + (size_t)nch * CCH * HWx;
        #pragma unroll
        for (int i = 0; i < NPF; ++i) {
            const int e = tid + i * 256;
            if (i < NPF - 1 || e < CHUNK_ELEMS) {
                const int cc  = e / CPLANE;
                const int rem = e - cc * CPLANE;
                const int row = rem / HALO_W;
                const int col = rem - row * HALO_W;
                const int gh = h0 - 1 + row;
                const int gw = w0 - 1 + col;
                float v = 0.f;
                if ((unsigned)gh < Hx && (unsigned)gw < Wx)
                    v = src[cc * HWx + gh * Wx + gw];
                sx[dbuf][e] = v;
            }
        }
    };

    // --- prologue: weights into LDS (batched loads) + chunk 0 into buf 0 ---
    #pragma unroll
    for (int j = 0; j < 24; ++j) sgp[tid + j * 256] = ws[WS_GPACK + tid + j * 256];
    #pragma unroll
    for (int j = 0; j < 16; ++j) scw[tid + j * 256] = ws[WS_CWT + tid + j * 256];
    #pragma unroll
    for (int j = 0; j < 9; ++j)  skern[tid + j * 256] = kws[tid + j * 256];
    satt[tid] = aws[tid];
    STAGE(0, 0);
    __syncthreads();

    // ================= PASS 1: guide convs -> argmax =================
    float ga[8];
    #pragma unroll
    for (int r = 0; r < 4; ++r) { ga[r] = g1b[r]; ga[4 + r] = g2b[r]; }

    #pragma unroll 1
    for (int ch = 0; ch < NCHUNK; ++ch) {
        const int buf = ch & 1;
        // stage next chunk into other buffer (ch==7 stages chunk 0 for pass 2)
        STAGE((ch + 1) & (NCHUNK - 1), buf ^ 1);

        float pg[8] = {0.f, 0.f, 0.f, 0.f, 0.f, 0.f, 0.f, 0.f};
        #pragma unroll
        for (int cc = 0; cc < CCH; ++cc) {
            const int c = ch * CCH + cc;
            float n[9];
            #pragma unroll
            for (int kh = 0; kh < 3; ++kh)
                #pragma unroll
                for (int kw = 0; kw < 3; ++kw)
                    n[kh * 3 + kw] = sx[buf][cc * CPLANE + (ty + kh) * HALO_W + (tx + kw)];
            const float4* gpv = (const float4*)(sgp + c * 96);   // uniform b128 broadcast
            #pragma unroll
            for (int rg = 0; rg < 8; ++rg) {          // rg = r*2+g
                const float4 q0 = gpv[rg * 3 + 0];
                const float4 q1 = gpv[rg * 3 + 1];
                const float4 q2 = gpv[rg * 3 + 2];
                float s = 0.f;                        // k-ascending, bit-identical chain
                s = fmaf(n[0], q0.x, s); s = fmaf(n[1], q0.y, s); s = fmaf(n[2], q0.z, s);
                s = fmaf(n[3], q0.w, s); s = fmaf(n[4], q1.x, s); s = fmaf(n[5], q1.y, s);
                s = fmaf(n[6], q1.z, s); s = fmaf(n[7], q1.w, s); s = fmaf(n[8], q2.x, s);
                pg[(rg >> 1) + (rg & 1) * 4] += s;    // static index (unrolled rg)
            }
        }
        #pragma unroll
        for (int i = 0; i < 8; ++i) ga[i] += pg[i];

        __syncthreads();
    }

    int r1 = 0, r2 = 0;
    {
        float m = ga[0];
        #pragma unroll
        for (int r = 1; r < 4; ++r) if (ga[r] > m) { m = ga[r]; r1 = r; }   // first-max ties
        float m2 = ga[4];
        #pragma unroll
        for (int r = 1; r < 4; ++r) if (ga[4 + r] > m2) { m2 = ga[4 + r]; r2 = r; }
    }

    // ================= PASS 2: routed depthwise + 1x1 =================
    float y[Cx];
    #pragma unroll
    for (int o = 0; o < Cx; ++o) y[o] = 0.f;

    #pragma unroll 1
    for (int ch = 0; ch < NCHUNK; ++ch) {
        const int buf = ch & 1;     // chunk 0 staged into buf 0 by pass-1's last phase
        if (ch < NCHUNK - 1)
            STAGE(ch + 1, buf ^ 1);

        #pragma unroll
        for (int cc = 0; cc < CCH; ++cc) {
            const int c = ch * CCH + cc;
            float n[9];
            #pragma unroll
            for (int kh = 0; kh < 3; ++kh)
                #pragma unroll
                for (int kw = 0; kw < 3; ++kw)
                    n[kh * 3 + kw] = sx[buf][cc * CPLANE + (ty + kh) * HALO_W + (tx + kw)];

            float dw = 0.f;
            #pragma unroll
            for (int k = 0; k < 9; ++k)
                dw = fmaf(n[k], skern[c * 36 + k * 4 + r1], dw);
            const float routed = dw > 0.f ? dw : 0.1f * dw;

            const float4* cwv = (const float4*)(scw + c * 64);   // uniform b128 broadcast
            #pragma unroll
            for (int q = 0; q < 16; ++q) {            // y statically indexed only
                const float4 w4 = cwv[q];
                y[q * 4 + 0] = fmaf(w4.x, routed, y[q * 4 + 0]);
                y[q * 4 + 1] = fmaf(w4.y, routed, y[q * 4 + 1]);
                y[q * 4 + 2] = fmaf(w4.z, routed, y[q * 4 + 2]);
                y[q * 4 + 3] = fmaf(w4.w, routed, y[q * 4 + 3]);
            }
        }

        if (ch < NCHUNK - 1)
            __syncthreads();
    }

    // --- epilogue: bias + CA branch (x center re-read) + store ---
    const int hh = h0 + ty;
    const int ww = w0 + tx;
    float* op = out + (size_t)b * Cx * HWx + hh * Wx + ww;
    const float* xp = xb + hh * Wx + ww;
    #pragma unroll
    for (int o = 0; o < Cx; ++o) {
        const float v = y[o] + convb[o] + xp[(size_t)o * HWx] * satt[o * 4 + r2];
        op[(size_t)o * HWx] = v;
    }
}

extern "C" void kernel_launch(void* const* d_in, const int* in_sizes, int n_in,
                              void* d_out, int out_size, void* d_ws, size_t ws_size,
                              hipStream_t stream) {
    const float* x0     = (const float*)d_in[0];
    const float* x_deg  = (const float*)d_in[1];
    const float* kw1    = (const float*)d_in[2];
    const float* kw2    = (const float*)d_in[3];
    const float* convw  = (const float*)d_in[4];
    const float* convb  = (const float*)d_in[5];
    const float* ca_w1  = (const float*)d_in[6];
    const float* ca_w2  = (const float*)d_in[7];
    const float* g1w    = (const float*)d_in[8];
    const float* g1b    = (const float*)d_in[9];
    const float* g2w    = (const float*)d_in[10];
    const float* g2b    = (const float*)d_in[11];
    float* outp = (float*)d_out;
    float* wsf  = (float*)d_ws;

    da_prep<<<Bx + 1, 256, 0, stream>>>(x_deg, kw1, kw2, convw, ca_w1, ca_w2,
                                        g1w, g2w, wsf);

    dim3 grid(Wx / TW, Hx / TH, Bx);   // 4 x 16 x 16 = 1024 blocks
    da_main<<<grid, 256, 0, stream>>>(x0, wsf, g1b, g2b, convb, outp);
}